// Round 15
// baseline (420.205 us; speedup 1.0000x reference)
//
#include <hip/hip_runtime.h>
#include <stdint.h>

typedef __bf16 bf16_t;
typedef __bf16 bf16x8 __attribute__((ext_vector_type(8)));
typedef float f32x4 __attribute__((ext_vector_type(4)));

// async global->LDS, 16B per lane; HW dest = wave-uniform base + lane*16
__device__ __forceinline__ void gload_lds16(const void* g, void* l) {
  __builtin_amdgcn_global_load_lds(
      (const __attribute__((address_space(1))) uint32_t*)g,
      (__attribute__((address_space(3))) uint32_t*)l, 16, 0, 0);
}

// ---------------- fused cast f32 -> bf16 for 3 buffers ----------------
__global__ void cast3_f32_bf16(const float* __restrict__ a, bf16_t* __restrict__ ao, int n4a,
                               const float* __restrict__ b, bf16_t* __restrict__ bo, int n4b,
                               const float* __restrict__ c, bf16_t* __restrict__ co, int n4c) {
  int i = blockIdx.x * blockDim.x + threadIdx.x;
  int stride = gridDim.x * blockDim.x;
  int total = n4a + n4b + n4c;
  for (int idx = i; idx < total; idx += stride) {
    const float* src; bf16_t* dst; int j = idx;
    if (j < n4a) { src = a; dst = ao; }
    else if ((j -= n4a) < n4b) { src = b; dst = bo; }
    else { j -= n4b; src = c; dst = co; }
    float4 v = reinterpret_cast<const float4*>(src)[j];
    union { bf16_t b[4]; uint2 u; } pk;
    pk.b[0] = (bf16_t)v.x; pk.b[1] = (bf16_t)v.y;
    pk.b[2] = (bf16_t)v.z; pk.b[3] = (bf16_t)v.w;
    reinterpret_cast<uint2*>(dst)[j] = pk.u;
  }
}

// ---- fat-wave GEMM: C[M][N] = A[M][K]*B[N][K]^T (+bias) ----
// BM=BN=256 BK=32, K=1024 (NT=32). 256 thr = 4 waves (2x2), wave tile
// 128x128 = 8x8 frags of 16x16x32 bf16. RATIONALE (r14 diagnosis): the
// r4-r14 plateau is LDS-BW-bound; 128x64 waves = 44 FLOP/LDS-byte < the
// ~48 needed. 128x128 -> 64 FLOP/byte: LDS 64KB rd + 32KB wr ~ 1130cy vs
// MFMA 1024cy per tile per CU -> MFMA-balanced.
// acc[8][8] f32x4 = 256 regs (AGPR half of unified file) + 128 frag
// (ping-pong) + ~30 addr ~= 415 < 450 no-spill (m08). 1 wave/SIMD: overlap
// is INTRA-wave: RD(t+1) issues before the 64-MFMA burst of t (1242 cy
// drains 16 ds_reads). 3-slot ring (96KB), staged 2 ahead.
// Per tile: [STAGE(t+2); vmcnt(8)] | BAR | RD(t+1) | MFMA(t) x64 | BAR
//  - leading BAR: after every wave's vmcnt(8) -> slot(t+1) fully landed
//    before any wave reads it.
//  - trailing BAR: reads of slot(t) (consumed by MFMA(t), data-dep complete)
//    ordered before tile t+1's STAGE overwriting slot(t-1)... (slot s is
//    restaged 3 tiles after its RD, 2 barriers in between).
// Swizzle: LDS[r][c16]=G[r][c16^((r>>1)&3)] both sides (r4: 0 conflicts).
// Grid: XCD x owns bx slab [x*8,x*8+8) (A-slab 4MB = its L2), bx-fast.
template <bool BF16_OUT>
__global__ __launch_bounds__(256, 1)
void gemm_fw(const bf16_t* __restrict__ A, const bf16_t* __restrict__ B,
             void* __restrict__ Cout, const float* __restrict__ bias, int N) {
  constexpr int K = 1024, NT = 32;
  __shared__ bf16_t Al[3][256 * 32];  // 3 x 16KB
  __shared__ bf16_t Bl[3][256 * 32];  // 3 x 16KB

  const int tid = threadIdx.x;
  const int l = tid & 63, w = tid >> 6;
  const int wm = w >> 1, wn = w & 1;

  const int bid = blockIdx.x;
  const int xcd = bid & 7, idx = bid >> 3;
  const int bx = xcd * 8 + (idx & 7);  // nbx = 64 (M = 16384)
  const int by = idx >> 3;
  const int m0 = bx * 256, n0 = by * 256;

  // staging (4KB/issue = 64 rows): thread t: row = t>>2, lds chunk t&3,
  // global chunk = (t&3) ^ ((row>>1)&3) = (t&3)^((t>>3)&3)  (inverse swz)
  const int ra = tid >> 2;
  const int ca = ((tid & 3) ^ ((tid >> 3) & 3)) * 8;
  const bf16_t* pA = A + (size_t)(m0 + ra) * K + ca;
  const bf16_t* pB = B + (size_t)(n0 + ra) * K + ca;

#define STAGE(t_, s_) do { const int kt_ = (t_) * 32;                  \
    gload_lds16(pA + kt_,                 &Al[s_][tid * 8]);           \
    gload_lds16(pA + (size_t)64 * K + kt_,  &Al[s_][2048 + tid * 8]);  \
    gload_lds16(pA + (size_t)128 * K + kt_, &Al[s_][4096 + tid * 8]);  \
    gload_lds16(pA + (size_t)192 * K + kt_, &Al[s_][6144 + tid * 8]);  \
    gload_lds16(pB + kt_,                 &Bl[s_][tid * 8]);           \
    gload_lds16(pB + (size_t)64 * K + kt_,  &Bl[s_][2048 + tid * 8]);  \
    gload_lds16(pB + (size_t)128 * K + kt_, &Bl[s_][4096 + tid * 8]);  \
    gload_lds16(pB + (size_t)192 * K + kt_, &Bl[s_][6144 + tid * 8]);  \
  } while (0)

  // frag reads: row = base + (l&15) + 16i (bases mult of 128) ->
  // (row>>1)&3 = (l>>1)&3 ; swizzled chunk = (l>>4) ^ ((l>>1)&3)
  const int abase = (wm * 128 + (l & 15)) * 32;
  const int bbase = (wn * 128 + (l & 15)) * 32;
  const int ck = ((l >> 4) ^ ((l >> 1) & 3)) * 8;

#define RD(af_, bf_, s_) do {                                                 \
    const bf16_t* As_ = Al[s_]; const bf16_t* Bs_ = Bl[s_];                   \
    _Pragma("unroll") for (int i = 0; i < 8; ++i)                             \
      af_[i] = *reinterpret_cast<const bf16x8*>(&As_[abase + i * 512 + ck]);  \
    _Pragma("unroll") for (int j = 0; j < 8; ++j)                             \
      bf_[j] = *reinterpret_cast<const bf16x8*>(&Bs_[bbase + j * 512 + ck]);  \
  } while (0)

#define MM64(af_, bf_)                                                        \
    _Pragma("unroll") for (int i = 0; i < 8; ++i)                             \
    _Pragma("unroll") for (int j = 0; j < 8; ++j)                             \
      acc[i][j] = __builtin_amdgcn_mfma_f32_16x16x32_bf16(                    \
          af_[i], bf_[j], acc[i][j], 0, 0, 0);

#define BARF() do { asm volatile("" ::: "memory");  \
    __builtin_amdgcn_s_barrier();                   \
    asm volatile("" ::: "memory"); } while (0)

#define TILE(t_, sl_, CA, CB, NA, NB) do {                                 \
    if ((t_) + 2 < NT) {                                                   \
      int st_ = (sl_) + 2; if (st_ >= 3) st_ -= 3;                         \
      STAGE((t_) + 2, st_);                                                \
      asm volatile("s_waitcnt vmcnt(8)" ::: "memory");                     \
    } else if ((t_) + 1 < NT) {                                            \
      asm volatile("s_waitcnt vmcnt(0)" ::: "memory");                     \
    }                                                                      \
    BARF();                                                                \
    if ((t_) + 1 < NT) {                                                   \
      int rd_ = (sl_) + 1; if (rd_ >= 3) rd_ -= 3;                         \
      RD(NA, NB, rd_);                                                     \
    }                                                                      \
    MM64(CA, CB);                                                          \
    BARF();                                                                \
  } while (0)

  f32x4 acc[8][8] = {};
  bf16x8 afA[8], bfA[8], afB[8], bfB[8];

  // prologue: stage slots 0,1; slot0 landed (slot1's 8 may fly); read tile0
  STAGE(0, 0); STAGE(1, 1);
  asm volatile("s_waitcnt vmcnt(8)" ::: "memory");
  BARF();
  RD(afA, bfA, 0);

  int sl = 0;
  for (int tt = 0; tt < NT; tt += 2) {
    TILE(tt, sl, afA, bfA, afB, bfB);
    sl = (sl == 2) ? 0 : sl + 1;
    TILE(tt + 1, sl, afB, bfB, afA, bfA);
    sl = (sl == 2) ? 0 : sl + 1;
  }
#undef STAGE
#undef RD
#undef MM64
#undef BARF
#undef TILE

  // ---- epilogue: C/D layout col = lane&15, row = (lane>>4)*4 + reg ----
  const int r0 = m0 + wm * 128 + (l >> 4) * 4;
  const int c0 = n0 + wn * 128 + (l & 15);
  if (BF16_OUT) {
    bf16_t* C = (bf16_t*)Cout;
#pragma unroll
    for (int i = 0; i < 8; ++i)
#pragma unroll
      for (int j = 0; j < 8; ++j)
#pragma unroll
        for (int r = 0; r < 4; ++r)
          C[(size_t)(r0 + i * 16 + r) * N + (c0 + j * 16)] = (bf16_t)acc[i][j][r];
  } else {
    float* C = (float*)Cout;
#pragma unroll
    for (int i = 0; i < 8; ++i)
#pragma unroll
      for (int j = 0; j < 8; ++j)
#pragma unroll
        for (int r = 0; r < 4; ++r)
          C[(size_t)(r0 + i * 16 + r) * N + (c0 + j * 16)] =
              acc[i][j][r] + bias[c0 + j * 16];
  }
}

// ---------------- per-token head-attention ----------------
__global__ __launch_bounds__(256)
void attn_heads(const bf16_t* __restrict__ qkv, bf16_t* __restrict__ out) {
  __shared__ float s[4][3072];
  const int w = threadIdx.x >> 6, l = threadIdx.x & 63;
  const size_t t = (size_t)blockIdx.x * 4 + w;
  const bf16_t* src = qkv + t * 3072;
#pragma unroll
  for (int i = 0; i < 6; ++i) {
    int f = (i * 64 + l) * 8;
    bf16x8 v = *reinterpret_cast<const bf16x8*>(&src[f]);
#pragma unroll
    for (int jj = 0; jj < 8; ++jj) s[w][f + jj] = (float)v[jj];
  }
  __syncthreads();

  const int h = l >> 2, ss = l & 3;
  float qr[16];
  const float* qb = &s[w][h * 192 + ss * 16];
#pragma unroll
  for (int d = 0; d < 16; ++d) qr[d] = qb[d];

  float sc[16];
#pragma unroll
  for (int g = 0; g < 16; ++g) {
    const float* kk = &s[w][g * 192 + 64 + ss * 16];
    float p = 0.f;
#pragma unroll
    for (int d = 0; d < 16; ++d) p += qr[d] * kk[d];
    p += __shfl_xor(p, 1);
    p += __shfl_xor(p, 2);
    sc[g] = p * 0.125f;
  }
  float m = sc[0];
#pragma unroll
  for (int g = 1; g < 16; ++g) m = fmaxf(m, sc[g]);
  float sum = 0.f;
#pragma unroll
  for (int g = 0; g < 16; ++g) { sc[g] = __expf(sc[g] - m); sum += sc[g]; }
  float inv = 1.f / sum;

  float o[16] = {};
#pragma unroll
  for (int g = 0; g < 16; ++g) {
    float a = sc[g] * inv;
    const float* vv = &s[w][g * 192 + 128 + ss * 16];
#pragma unroll
    for (int d = 0; d < 16; ++d) o[d] += a * vv[d];
  }
  union { bf16_t b[16]; uint4 u[2]; } pk;
#pragma unroll
  for (int d = 0; d < 16; ++d) pk.b[d] = (bf16_t)o[d];
  uint4* dst = reinterpret_cast<uint4*>(out + t * 1024 + h * 64 + ss * 16);
  dst[0] = pk.u[0];
  dst[1] = pk.u[1];
}

// ---------------- launch ----------------
extern "C" void kernel_launch(void* const* d_in, const int* in_sizes, int n_in,
                              void* d_out, int out_size, void* d_ws, size_t ws_size,
                              hipStream_t stream) {
  const float* x     = (const float*)d_in[0];  // [8,2048,1024]
  const float* Wqkv  = (const float*)d_in[1];  // [3072,1024]
  const float* Wproj = (const float*)d_in[2];  // [1024,1024]
  const float* bproj = (const float*)d_in[3];  // [1024]
  float* out = (float*)d_out;

  const int M = 8 * 2048;   // 16384 tokens -> 64 bx blocks of 256
  const int DM = 1024;
  const int F = 3072;

  char* ws = (char*)d_ws;
  bf16_t* xb     = (bf16_t*)ws;  ws += (size_t)M * DM * 2;
  bf16_t* wqkvb  = (bf16_t*)ws;  ws += (size_t)F * DM * 2;
  bf16_t* wprojb = (bf16_t*)ws;  ws += (size_t)DM * DM * 2;
  bf16_t* qkvb   = (bf16_t*)ws;  ws += (size_t)M * F * 2;
  bf16_t* attnb  = (bf16_t*)ws;

  cast3_f32_bf16<<<2048, 256, 0, stream>>>(x, xb, M * DM / 4,
                                           Wqkv, wqkvb, F * DM / 4,
                                           Wproj, wprojb, DM * DM / 4);

  // GEMM1: [16384,1024] x [3072,1024]^T -> bf16 [16384,3072]
  gemm_fw<true><<<(M / 256) * (F / 256), 256, 0, stream>>>(
      xb, wqkvb, (void*)qkvb, nullptr, F);

  attn_heads<<<M / 4, 256, 0, stream>>>(qkvb, attnb);

  // GEMM2: [16384,1024] x [1024,1024]^T -> f32 [16384,1024] + bias
  gemm_fw<false><<<(M / 256) * (DM / 256), 256, 0, stream>>>(
      attnb, wprojb, (void*)out, bproj, DM);
}

// Round 16
// 205.570 us; speedup vs baseline: 2.0441x; 2.0441x over previous
//
#include <hip/hip_runtime.h>
#include <stdint.h>

typedef __bf16 bf16_t;
typedef __bf16 bf16x8 __attribute__((ext_vector_type(8)));
typedef float f32x4 __attribute__((ext_vector_type(4)));

// async global->LDS, 16B per lane; HW dest = wave-uniform base + lane*16
__device__ __forceinline__ void gload_lds16(const void* g, void* l) {
  __builtin_amdgcn_global_load_lds(
      (const __attribute__((address_space(1))) uint32_t*)g,
      (__attribute__((address_space(3))) uint32_t*)l, 16, 0, 0);
}

// ---------------- fused cast f32 -> bf16 for 3 buffers ----------------
__global__ void cast3_f32_bf16(const float* __restrict__ a, bf16_t* __restrict__ ao, int n4a,
                               const float* __restrict__ b, bf16_t* __restrict__ bo, int n4b,
                               const float* __restrict__ c, bf16_t* __restrict__ co, int n4c) {
  int i = blockIdx.x * blockDim.x + threadIdx.x;
  int stride = gridDim.x * blockDim.x;
  int total = n4a + n4b + n4c;
  for (int idx = i; idx < total; idx += stride) {
    const float* src; bf16_t* dst; int j = idx;
    if (j < n4a) { src = a; dst = ao; }
    else if ((j -= n4a) < n4b) { src = b; dst = bo; }
    else { j -= n4b; src = c; dst = co; }
    float4 v = reinterpret_cast<const float4*>(src)[j];
    union { bf16_t b[4]; uint2 u; } pk;
    pk.b[0] = (bf16_t)v.x; pk.b[1] = (bf16_t)v.y;
    pk.b[2] = (bf16_t)v.z; pk.b[3] = (bf16_t)v.w;
    reinterpret_cast<uint2*>(dst)[j] = pk.u;
  }
}

// ---- pinned-pipeline GEMM: C[M][N] = A[M][K]*B[N][K]^T (+bias) ----
// BM=BN=256 BK=32, K=1024 (NT=32). 512 thr = 8 waves (2M x 4N), wave tile
// 128x64 = 8x4 frags 16x16x32 bf16. 4-slot LDS ring (128KB), staged 3 ahead.
// THEORY (r15): all r4-r14 variants serialize because the compiler SINKS the
// ds_reads down to their consuming MFMAs (register-pressure heuristic) —
// source-level pipelining never survives to the .s. FIX: per tile, issue
// RD(t+1) 12 ds_reads + STAGE(t+3) 4 gloads, then ONE sched_barrier(0) pin,
// then 32 MFMA on tile-t regs. NO manual lgkm waits: the compiler's precise
// counted wait before MFMA(t) covers only tile-t frags (drained under t-1's
// MFMAs), so t+1's reads stay in flight under the burst.
// Ring-4 safety: STAGE(t+3) overwrites slot(t-1); its reads (RD at t-2)
// drained before MM32(t-1) [data-dep] => before t-1's barrier; STAGE issues
// after that barrier. Cross-wave identical via the shared barrier.
// Gate: RD(t+1) at tile t needs stage(t+1) landed => end-of-tile vmcnt(4)
// (only stage(t+3)'s 4 newer); vmcnt(0) at t=NT-3; prologue vmcnt(4).
// Swizzle: LDS[r][c16]=G[r][c16^((r>>1)&3)] both sides (r4: 0 conflicts).
// Grid: XCD x owns bx slab [x*8,x*8+8) (A-slab 4MB = its L2), bx-fast.
template <bool BF16_OUT>
__global__ __launch_bounds__(512, 2)
void gemm_pin(const bf16_t* __restrict__ A, const bf16_t* __restrict__ B,
              void* __restrict__ Cout, const float* __restrict__ bias, int N) {
  constexpr int K = 1024, NT = 32;
  __shared__ bf16_t Al[4][256 * 32];  // 4 x 16KB
  __shared__ bf16_t Bl[4][256 * 32];  // 4 x 16KB

  const int tid = threadIdx.x;
  const int l = tid & 63, w = tid >> 6;
  const int wm = w >> 2, wn = w & 3;

  const int bid = blockIdx.x;
  const int xcd = bid & 7, idx = bid >> 3;
  const int bx = xcd * 8 + (idx & 7);  // nbx = 64 (M = 16384)
  const int by = idx >> 3;
  const int m0 = bx * 256, n0 = by * 256;

  // staging: thread t: row = t>>2 (+128 second issue), lds chunk t&3,
  // global chunk = (t&3) ^ ((row>>1)&3) = (t&3)^((t>>3)&3)  (inverse swz)
  const int ra = tid >> 2;
  const int ca = ((tid & 3) ^ ((tid >> 3) & 3)) * 8;
  const bf16_t* pA0 = A + (size_t)(m0 + ra) * K + ca;
  const bf16_t* pA1 = A + (size_t)(m0 + 128 + ra) * K + ca;
  const bf16_t* pB0 = B + (size_t)(n0 + ra) * K + ca;
  const bf16_t* pB1 = B + (size_t)(n0 + 128 + ra) * K + ca;
  const int wb = w * 512;  // wave's 1KB segment within an 8KB issue

#define STAGE(t_, s_) do { const int kt_ = (t_) * 32;  \
    gload_lds16(pA0 + kt_, &Al[s_][wb]);               \
    gload_lds16(pA1 + kt_, &Al[s_][4096 + wb]);        \
    gload_lds16(pB0 + kt_, &Bl[s_][wb]);               \
    gload_lds16(pB1 + kt_, &Bl[s_][4096 + wb]); } while (0)

  // frag reads: row = base + (l&15) + 16i -> (row>>1)&3 = (l>>1)&3
  const int abase = (wm * 128 + (l & 15)) * 32;
  const int bbase = (wn * 64 + (l & 15)) * 32;
  const int ck = ((l >> 4) ^ ((l >> 1) & 3)) * 8;

#define RD(af_, bf_, s_) do {                                                  \
    const bf16_t* As_ = Al[s_]; const bf16_t* Bs_ = Bl[s_];                    \
    _Pragma("unroll") for (int i = 0; i < 8; ++i)                              \
      af_[i] = *reinterpret_cast<const bf16x8*>(&As_[abase + i * 512 + ck]);   \
    _Pragma("unroll") for (int j = 0; j < 4; ++j)                              \
      bf_[j] = *reinterpret_cast<const bf16x8*>(&Bs_[bbase + j * 512 + ck]);   \
  } while (0)

#define MM32(af_, bf_)                                                         \
    _Pragma("unroll") for (int i = 0; i < 8; ++i)                              \
    _Pragma("unroll") for (int j = 0; j < 4; ++j)                              \
      acc[i][j] = __builtin_amdgcn_mfma_f32_16x16x32_bf16(                     \
          af_[i], bf_[j], acc[i][j], 0, 0, 0);

#define BARF() do { asm volatile("" ::: "memory");  \
    __builtin_amdgcn_s_barrier();                   \
    asm volatile("" ::: "memory"); } while (0)

#define TILE(t_, CA, CB, NA, NB) do {                                      \
    if ((t_) + 1 < NT) RD(NA, NB, ((t_) + 1) & 3);                         \
    if ((t_) + 3 < NT) STAGE((t_) + 3, ((t_) + 3) & 3);                    \
    __builtin_amdgcn_sched_barrier(0);  /* pin reads+stage above MFMAs */  \
    MM32(CA, CB);                                                          \
    if ((t_) + 4 < NT)      asm volatile("s_waitcnt vmcnt(4)" ::: "memory"); \
    else if ((t_) + 3 == NT - 1 + 1 - 1 && false) {}                       \
    else if ((t_) == NT - 3) asm volatile("s_waitcnt vmcnt(0)" ::: "memory"); \
    else if ((t_) < NT - 3)  asm volatile("s_waitcnt vmcnt(4)" ::: "memory"); \
    BARF();                                                                \
  } while (0)

  f32x4 acc[8][4] = {};
  bf16x8 afA[8], bfA[4], afB[8], bfB[4];

  // prologue: stage slots 0,1,2; slots 0,1 landed (slot2's 4 may fly)
  STAGE(0, 0); STAGE(1, 1); STAGE(2, 2);
  asm volatile("s_waitcnt vmcnt(4)" ::: "memory");
  BARF();
  RD(afA, bfA, 0);

  for (int tt = 0; tt < NT; tt += 2) {
    TILE(tt, afA, bfA, afB, bfB);
    TILE(tt + 1, afB, bfB, afA, bfA);
  }
#undef STAGE
#undef RD
#undef MM32
#undef BARF
#undef TILE

  // ---- epilogue: C/D layout col = lane&15, row = (lane>>4)*4 + reg ----
  const int r0 = m0 + wm * 128 + (l >> 4) * 4;
  const int c0 = n0 + wn * 64 + (l & 15);
  if (BF16_OUT) {
    bf16_t* C = (bf16_t*)Cout;
#pragma unroll
    for (int i = 0; i < 8; ++i)
#pragma unroll
      for (int j = 0; j < 4; ++j)
#pragma unroll
        for (int r = 0; r < 4; ++r)
          C[(size_t)(r0 + i * 16 + r) * N + (c0 + j * 16)] = (bf16_t)acc[i][j][r];
  } else {
    float* C = (float*)Cout;
#pragma unroll
    for (int i = 0; i < 8; ++i)
#pragma unroll
      for (int j = 0; j < 4; ++j)
#pragma unroll
        for (int r = 0; r < 4; ++r)
          C[(size_t)(r0 + i * 16 + r) * N + (c0 + j * 16)] =
              acc[i][j][r] + bias[c0 + j * 16];
  }
}

// ---------------- per-token head-attention ----------------
__global__ __launch_bounds__(256)
void attn_heads(const bf16_t* __restrict__ qkv, bf16_t* __restrict__ out) {
  __shared__ float s[4][3072];
  const int w = threadIdx.x >> 6, l = threadIdx.x & 63;
  const size_t t = (size_t)blockIdx.x * 4 + w;
  const bf16_t* src = qkv + t * 3072;
#pragma unroll
  for (int i = 0; i < 6; ++i) {
    int f = (i * 64 + l) * 8;
    bf16x8 v = *reinterpret_cast<const bf16x8*>(&src[f]);
#pragma unroll
    for (int jj = 0; jj < 8; ++jj) s[w][f + jj] = (float)v[jj];
  }
  __syncthreads();

  const int h = l >> 2, ss = l & 3;
  float qr[16];
  const float* qb = &s[w][h * 192 + ss * 16];
#pragma unroll
  for (int d = 0; d < 16; ++d) qr[d] = qb[d];

  float sc[16];
#pragma unroll
  for (int g = 0; g < 16; ++g) {
    const float* kk = &s[w][g * 192 + 64 + ss * 16];
    float p = 0.f;
#pragma unroll
    for (int d = 0; d < 16; ++d) p += qr[d] * kk[d];
    p += __shfl_xor(p, 1);
    p += __shfl_xor(p, 2);
    sc[g] = p * 0.125f;
  }
  float m = sc[0];
#pragma unroll
  for (int g = 1; g < 16; ++g) m = fmaxf(m, sc[g]);
  float sum = 0.f;
#pragma unroll
  for (int g = 0; g < 16; ++g) { sc[g] = __expf(sc[g] - m); sum += sc[g]; }
  float inv = 1.f / sum;

  float o[16] = {};
#pragma unroll
  for (int g = 0; g < 16; ++g) {
    float a = sc[g] * inv;
    const float* vv = &s[w][g * 192 + 128 + ss * 16];
#pragma unroll
    for (int d = 0; d < 16; ++d) o[d] += a * vv[d];
  }
  union { bf16_t b[16]; uint4 u[2]; } pk;
#pragma unroll
  for (int d = 0; d < 16; ++d) pk.b[d] = (bf16_t)o[d];
  uint4* dst = reinterpret_cast<uint4*>(out + t * 1024 + h * 64 + ss * 16);
  dst[0] = pk.u[0];
  dst[1] = pk.u[1];
}

// ---------------- launch ----------------
extern "C" void kernel_launch(void* const* d_in, const int* in_sizes, int n_in,
                              void* d_out, int out_size, void* d_ws, size_t ws_size,
                              hipStream_t stream) {
  const float* x     = (const float*)d_in[0];  // [8,2048,1024]
  const float* Wqkv  = (const float*)d_in[1];  // [3072,1024]
  const float* Wproj = (const float*)d_in[2];  // [1024,1024]
  const float* bproj = (const float*)d_in[3];  // [1024]
  float* out = (float*)d_out;

  const int M = 8 * 2048;   // 16384 tokens -> 64 bx blocks of 256
  const int DM = 1024;
  const int F = 3072;

  char* ws = (char*)d_ws;
  bf16_t* xb     = (bf16_t*)ws;  ws += (size_t)M * DM * 2;
  bf16_t* wqkvb  = (bf16_t*)ws;  ws += (size_t)F * DM * 2;
  bf16_t* wprojb = (bf16_t*)ws;  ws += (size_t)DM * DM * 2;
  bf16_t* qkvb   = (bf16_t*)ws;  ws += (size_t)M * F * 2;
  bf16_t* attnb  = (bf16_t*)ws;

  cast3_f32_bf16<<<2048, 256, 0, stream>>>(x, xb, M * DM / 4,
                                           Wqkv, wqkvb, F * DM / 4,
                                           Wproj, wprojb, DM * DM / 4);

  // GEMM1: [16384,1024] x [3072,1024]^T -> bf16 [16384,3072]
  gemm_pin<true><<<(M / 256) * (F / 256), 512, 0, stream>>>(
      xb, wqkvb, (void*)qkvb, nullptr, F);

  attn_heads<<<M / 4, 256, 0, stream>>>(qkvb, attnb);

  // GEMM2: [16384,1024] x [1024,1024]^T -> f32 [16384,1024] + bias
  gemm_pin<false><<<(M / 256) * (DM / 256), 512, 0, stream>>>(
      attnb, wprojb, (void*)out, bproj, DM);
}